// Round 4
// baseline (19.664 us; speedup 1.0000x reference)
//
#include <hip/hip_runtime.h>
#include <math.h>

// SpheresRasterizer: B=1, N=1024 points, H=W=256, K=8.
// Round 4: (a) hoist point transform to a tiny pre-pass kernel (d_ws holds
// float4 {sx, sy, z_view, r2eff}); (b) raster blocks cull+compact to LDS as
// before, but the per-pixel scan uses wave-register broadcast: each wave
// loads survivor[base+lane] into registers once per 64 points, then loops k
// with v_readlane (uniform index) -> zero memory ops in the hot loop.
// Exact per-pixel arithmetic and ascending-index processing order preserved.

#define KPP 8

__global__ __launch_bounds__(256) void transform_kernel(
    const float* __restrict__ points,   // B*N*3
    const float* __restrict__ radius,   // B*N
    const float* __restrict__ w2v,      // B*16
    const float* __restrict__ proj,     // B*16
    float4* __restrict__ ws,            // B*N transformed
    int B, int N)
{
    int t = blockIdx.x * blockDim.x + threadIdx.x;
    if (t >= B * N) return;
    int b = t / N;
    const float* M1 = w2v  + (size_t)b * 16;
    const float* M2 = proj + (size_t)b * 16;
    float x = points[(size_t)t * 3 + 0];
    float y = points[(size_t)t * 3 + 1];
    float z = points[(size_t)t * 3 + 2];
    float vx = ((x * M1[0] + y * M1[4]) + z * M1[8])  + M1[12];
    float vy = ((x * M1[1] + y * M1[5]) + z * M1[9])  + M1[13];
    float vz = ((x * M1[2] + y * M1[6]) + z * M1[10]) + M1[14];
    float vw = ((x * M1[3] + y * M1[7]) + z * M1[11]) + M1[15];
    float w1 = (fabsf(vw) < 1e-8f) ? 1e-8f : vw;
    vx /= w1; vy /= w1; vz /= w1;
    float sx = ((vx * M2[0] + vy * M2[4]) + vz * M2[8])  + M2[12];
    float sy = ((vx * M2[1] + vy * M2[5]) + vz * M2[9])  + M2[13];
    float sw = ((vx * M2[3] + vy * M2[7]) + vz * M2[11]) + M2[15];
    float w2 = (fabsf(sw) < 1e-8f) ? 1e-8f : sw;
    sx /= w2; sy /= w2;
    float r = radius[t];
    float r2eff = (vz > 0.0f) ? r * r : -1.0f;
    ws[t] = make_float4(sx, sy, vz, r2eff);
}

__global__ __launch_bounds__(256) void sphere_raster_kernel(
    const float4* __restrict__ ws,      // B*N transformed points
    float* __restrict__ out,            // 3 * B*H*W*KPP floats
    int B, int N, int H, int W)
{
    extern __shared__ char smem[];
    float4* cmp  = (float4*)smem;                              // N entries
    int*    cidx = (int*)(smem + (size_t)N * sizeof(float4));  // N entries
    __shared__ int wsum[4];

    const int TS = 16;
    const int tilesX = W / TS;
    const int tile   = blockIdx.x % (tilesX * (H / TS));
    const int b      = blockIdx.x / (tilesX * (H / TS));
    const int tx0    = (tile % tilesX) * TS;
    const int ty0    = (tile / tilesX) * TS;
    const int j      = tx0 + (threadIdx.x & (TS - 1));
    const int i      = ty0 + (threadIdx.x >> 4);
    const int lane   = threadIdx.x & 63;
    const int wid    = threadIdx.x >> 6;

    const double halfd = 1.0 - 1.0 / (double)W;
    const double step  = 2.0 * halfd / (double)(W - 1);
    const float px = (float)(halfd - (double)j * step);
    const float py = (float)(halfd - (double)i * step);

    const float cx = (float)(halfd - ((double)tx0 + (TS - 1) * 0.5) * step);
    const float cy = (float)(halfd - ((double)ty0 + (TS - 1) * 0.5) * step);
    const float hext = (float)(((TS - 1) * 0.5 + 1.0) * step);  // +1px inflation

    // ---- Phase 1: load 4 precomputed points/thread, cull to tile box ----
    const int t0 = threadIdx.x * 4;         // N == 4*blockDim, ascending order
    const float4* base4 = ws + (size_t)b * N + t0;
    float4 P[4];
    int keep[4];
    int c = 0;
#pragma unroll
    for (int s = 0; s < 4; ++s) {
        float4 p = base4[s];
        float dxm = fmaxf(0.0f, fabsf(p.x - cx) - hext);
        float dym = fmaxf(0.0f, fabsf(p.y - cy) - hext);
        float dmin2 = dxm * dxm + dym * dym;
        keep[s] = (dmin2 <= p.w + 1e-6f) ? 1 : 0;
        P[s] = p;
        c += keep[s];
    }

    // ---- order-preserving compaction ----
    int pre = c;
#pragma unroll
    for (int d = 1; d < 64; d <<= 1) {
        int v = __shfl_up(pre, d);
        if (lane >= d) pre += v;
    }
    if (lane == 63) wsum[wid] = pre;
    __syncthreads();
    int wbase = 0, M = 0;
#pragma unroll
    for (int w = 0; w < 4; ++w) {
        int s = wsum[w];
        if (w < wid) wbase += s;
        M += s;
    }
    int pos = wbase + (pre - c);
#pragma unroll
    for (int s = 0; s < 4; ++s) {
        if (keep[s]) { cmp[pos] = P[s]; cidx[pos] = t0 + s; ++pos; }
    }
    __syncthreads();

    // ---- Phase 2: wave-register broadcast scan (no memory in hot loop) ----
    float zb[KPP]; int id[KPP]; float dd[KPP];
#pragma unroll
    for (int k = 0; k < KPP; ++k) { zb[k] = INFINITY; id[k] = -1; dd[k] = -1.0f; }

    for (int bb = 0; bb < M; bb += 64) {
        int li = bb + lane;
        float4 pl;
        int il;
        if (li < M) { pl = cmp[li]; il = cidx[li]; }
        else { pl = make_float4(0.0f, 0.0f, INFINITY, -1.0f); il = -1; }
        int cnt = (M - bb < 64) ? (M - bb) : 64;
        for (int k = 0; k < cnt; ++k) {
            float sx = __int_as_float(__builtin_amdgcn_readlane(__float_as_int(pl.x), k));
            float sy = __int_as_float(__builtin_amdgcn_readlane(__float_as_int(pl.y), k));
            float sz = __int_as_float(__builtin_amdgcn_readlane(__float_as_int(pl.z), k));
            float sw = __int_as_float(__builtin_amdgcn_readlane(__float_as_int(pl.w), k));
            int   si = __builtin_amdgcn_readlane(il, k);
            float dx = sx - px;
            float dy = sy - py;
            float dist2 = __fadd_rn(__fmul_rn(dx, dx), __fmul_rn(dy, dy));
            if ((dist2 <= sw) && (sz < zb[KPP - 1])) {
                float zc = sz; int ic = si; float dc = dist2;
#pragma unroll
                for (int k2 = 0; k2 < KPP; ++k2) {
                    bool lt = (zc < zb[k2]);
                    float tz = zb[k2]; int ti = id[k2]; float td = dd[k2];
                    if (lt) { zb[k2] = zc; id[k2] = ic; dd[k2] = dc; zc = tz; ic = ti; dc = td; }
                }
            }
        }
    }

    // ---- Phase 3: write outputs ----
    const size_t pix   = ((size_t)b * H + i) * W + j;
    const size_t plane = (size_t)B * H * W * KPP;
    float vidx[KPP], vzbf[KPP], vdst[KPP];
#pragma unroll
    for (int k = 0; k < KPP; ++k) {
        bool valid = (zb[k] != INFINITY);
        vidx[k] = valid ? (float)id[k] : -1.0f;
        vzbf[k] = valid ? zb[k]        : -1.0f;
        vdst[k] = valid ? dd[k]        : -1.0f;
    }
    float* oidx = out + pix * KPP;
    float* ozbf = out + plane + pix * KPP;
    float* odst = out + 2 * plane + pix * KPP;
    *(float4*)(oidx)     = make_float4(vidx[0], vidx[1], vidx[2], vidx[3]);
    *(float4*)(oidx + 4) = make_float4(vidx[4], vidx[5], vidx[6], vidx[7]);
    *(float4*)(ozbf)     = make_float4(vzbf[0], vzbf[1], vzbf[2], vzbf[3]);
    *(float4*)(ozbf + 4) = make_float4(vzbf[4], vzbf[5], vzbf[6], vzbf[7]);
    *(float4*)(odst)     = make_float4(vdst[0], vdst[1], vdst[2], vdst[3]);
    *(float4*)(odst + 4) = make_float4(vdst[4], vdst[5], vdst[6], vdst[7]);
}

extern "C" void kernel_launch(void* const* d_in, const int* in_sizes, int n_in,
                              void* d_out, int out_size, void* d_ws, size_t ws_size,
                              hipStream_t stream) {
    const float* points = (const float*)d_in[0];
    const float* radius = (const float*)d_in[1];
    const float* w2v    = (const float*)d_in[2];
    const float* proj   = (const float*)d_in[3];
    int B = in_sizes[2] / 16;
    if (B < 1) B = 1;
    int N = in_sizes[1] / B;
    int HW = out_size / (3 * B * KPP);
    int H = 1;
    while ((H + 1) * (H + 1) <= HW) ++H;     // integer sqrt
    int W = H;

    float4* ws = (float4*)d_ws;              // B*N*16 bytes

    int total = B * N;
    transform_kernel<<<(total + 255) / 256, 256, 0, stream>>>(
        points, radius, w2v, proj, ws, B, N);

    int tiles = (W / 16) * (H / 16);
    size_t shmem = (size_t)N * (sizeof(float4) + sizeof(int));
    sphere_raster_kernel<<<B * tiles, 256, shmem, stream>>>(
        ws, (float*)d_out, B, N, H, W);
}

// Round 5
// 14.351 us; speedup vs baseline: 1.3702x; 1.3702x over previous
//
#include <hip/hip_runtime.h>
#include <math.h>

// SpheresRasterizer: B=1, N=1024 points, H=W=256, K=8.
// Round 5: round-3 fused structure (16x16 tiles, inline bit-exact transform,
// order-preserving compaction) + phase-2 latency fixes ONLY:
//   - sentinel-pad compacted list to a multiple of 16 (r2eff=-1 => never
//     inside), eliminating the scalar tail loop entirely;
//   - double-buffered 8-wide LDS batches (load B, process A, load A', process
//     B) so LDS latency hides under insertion processing.

#define KPP 8
#define BW  8   // batch width (points per half-batch)

__global__ __launch_bounds__(256) void sphere_raster_kernel(
    const float* __restrict__ points,   // B*N*3
    const float* __restrict__ radius,   // B*N
    const float* __restrict__ w2v,      // B*16
    const float* __restrict__ proj,     // B*16
    float* __restrict__ out,            // 3 * B*H*W*KPP floats
    int B, int N, int H, int W)
{
    extern __shared__ char smem[];
    float4* cmp  = (float4*)smem;                                     // N+2*BW
    int*    cidx = (int*)(smem + (size_t)(N + 2 * BW) * sizeof(float4));
    __shared__ int wsum[4];

    const int TS = 16;
    const int tilesX = W / TS;
    const int tile   = blockIdx.x % (tilesX * (H / TS));
    const int b      = blockIdx.x / (tilesX * (H / TS));
    const int tx0    = (tile % tilesX) * TS;
    const int ty0    = (tile / tilesX) * TS;
    const int j      = tx0 + (threadIdx.x & (TS - 1));
    const int i      = ty0 + (threadIdx.x >> 4);
    const int lane   = threadIdx.x & 63;
    const int wid    = threadIdx.x >> 6;

    const float* M1 = w2v  + (size_t)b * 16;
    const float* M2 = proj + (size_t)b * 16;

    const double halfd = 1.0 - 1.0 / (double)W;
    const double step  = 2.0 * halfd / (double)(W - 1);
    const float px = (float)(halfd - (double)j * step);
    const float py = (float)(halfd - (double)i * step);

    const float cx = (float)(halfd - ((double)tx0 + (TS - 1) * 0.5) * step);
    const float cy = (float)(halfd - ((double)ty0 + (TS - 1) * 0.5) * step);
    const float hext = (float)(((TS - 1) * 0.5 + 1.0) * step);  // +1px inflation

    // ---- Phase 1: transform 4 contiguous points/thread, cull to tile box ----
    // (bit-exact copy of round 3 — do NOT change numerics)
    const int t0 = threadIdx.x * 4;         // N == 4*blockDim
    float4 P[4];
    int keep[4];
    int c = 0;

    const float4* pv = (const float4*)(points + ((size_t)b * N + t0) * 3);
    float4 q0 = pv[0], q1 = pv[1], q2 = pv[2];
    float4 rr = *(const float4*)(radius + (size_t)b * N + t0);
    float xs[4] = {q0.x, q0.w, q1.z, q2.y};
    float ys[4] = {q0.y, q1.x, q1.w, q2.z};
    float zs[4] = {q0.z, q1.y, q2.x, q2.w};
    float rv[4] = {rr.x, rr.y, rr.z, rr.w};

#pragma unroll
    for (int s = 0; s < 4; ++s) {
        float x = xs[s], y = ys[s], z = zs[s];
        float vx = ((x * M1[0] + y * M1[4]) + z * M1[8])  + M1[12];
        float vy = ((x * M1[1] + y * M1[5]) + z * M1[9])  + M1[13];
        float vz = ((x * M1[2] + y * M1[6]) + z * M1[10]) + M1[14];
        float vw = ((x * M1[3] + y * M1[7]) + z * M1[11]) + M1[15];
        float w1 = (fabsf(vw) < 1e-8f) ? 1e-8f : vw;
        vx /= w1; vy /= w1; vz /= w1;
        float sx = ((vx * M2[0] + vy * M2[4]) + vz * M2[8])  + M2[12];
        float sy = ((vx * M2[1] + vy * M2[5]) + vz * M2[9])  + M2[13];
        float sw = ((vx * M2[3] + vy * M2[7]) + vz * M2[11]) + M2[15];
        float w2 = (fabsf(sw) < 1e-8f) ? 1e-8f : sw;
        sx /= w2; sy /= w2;
        float r = rv[s];
        float r2eff = (vz > 0.0f) ? r * r : -1.0f;
        float dxm = fmaxf(0.0f, fabsf(sx - cx) - hext);
        float dym = fmaxf(0.0f, fabsf(sy - cy) - hext);
        float dmin2 = dxm * dxm + dym * dym;
        keep[s] = (dmin2 <= r2eff + 1e-6f) ? 1 : 0;
        P[s] = make_float4(sx, sy, vz, r2eff);
        c += keep[s];
    }

    // ---- order-preserving compaction (unchanged) ----
    int pre = c;
#pragma unroll
    for (int d = 1; d < 64; d <<= 1) {
        int v = __shfl_up(pre, d);
        if (lane >= d) pre += v;
    }
    if (lane == 63) wsum[wid] = pre;
    __syncthreads();
    int wbase = 0, M = 0;
#pragma unroll
    for (int w = 0; w < 4; ++w) {
        int s = wsum[w];
        if (w < wid) wbase += s;
        M += s;
    }
    int pos = wbase + (pre - c);
#pragma unroll
    for (int s = 0; s < 4; ++s) {
        if (keep[s]) { cmp[pos] = P[s]; cidx[pos] = t0 + s; ++pos; }
    }

    // ---- sentinel padding to a multiple of 2*BW (kills the tail loop) ----
    const int Mpad = (M + 2 * BW - 1) & ~(2 * BW - 1);
    if (threadIdx.x < Mpad - M) {
        cmp[M + threadIdx.x]  = make_float4(0.0f, 0.0f, 0.0f, -1.0f); // never inside
        cidx[M + threadIdx.x] = -1;
    }
    __syncthreads();

    // ---- Phase 2: double-buffered 8-wide batched scan ----
    float zb[KPP]; int id[KPP]; float dd[KPP];
#pragma unroll
    for (int k = 0; k < KPP; ++k) { zb[k] = INFINITY; id[k] = -1; dd[k] = -1.0f; }

    auto process = [&](const float4* pp, const int* ii) {
#pragma unroll
        for (int u = 0; u < BW; ++u) {
            float dx = pp[u].x - px;
            float dy = pp[u].y - py;
            float dist2 = __fadd_rn(__fmul_rn(dx, dx), __fmul_rn(dy, dy));
            if ((dist2 <= pp[u].w) && (pp[u].z < zb[KPP - 1])) {
                float zc = pp[u].z; int ic = ii[u]; float dc = dist2;
#pragma unroll
                for (int k2 = 0; k2 < KPP; ++k2) {
                    bool lt = (zc < zb[k2]);
                    float tz = zb[k2]; int ti = id[k2]; float td = dd[k2];
                    if (lt) { zb[k2] = zc; id[k2] = ic; dd[k2] = dc; zc = tz; ic = ti; dc = td; }
                }
            }
        }
    };

    float4 pa[BW]; int ia[BW];
    float4 pb[BW]; int ib[BW];

    // preload batch A = [0, BW)  (safe: LDS allocated with 2*BW slack)
#pragma unroll
    for (int u = 0; u < BW; ++u) pa[u] = cmp[u];
    {
        int4 t4a = *(const int4*)&cidx[0];
        int4 t4b = *(const int4*)&cidx[4];
        ia[0]=t4a.x; ia[1]=t4a.y; ia[2]=t4a.z; ia[3]=t4a.w;
        ia[4]=t4b.x; ia[5]=t4b.y; ia[6]=t4b.z; ia[7]=t4b.w;
    }

    for (int n = 0; n < Mpad; n += 2 * BW) {
        // issue loads for batch B = [n+BW, n+2BW)  (always within Mpad)
#pragma unroll
        for (int u = 0; u < BW; ++u) pb[u] = cmp[n + BW + u];
        {
            int4 t4a = *(const int4*)&cidx[n + BW];
            int4 t4b = *(const int4*)&cidx[n + BW + 4];
            ib[0]=t4a.x; ib[1]=t4a.y; ib[2]=t4a.z; ib[3]=t4a.w;
            ib[4]=t4b.x; ib[5]=t4b.y; ib[6]=t4b.z; ib[7]=t4b.w;
        }
        process(pa, ia);
        // issue loads for next batch A = [n+2BW, n+3BW) if it exists
        if (n + 2 * BW < Mpad) {
#pragma unroll
            for (int u = 0; u < BW; ++u) pa[u] = cmp[n + 2 * BW + u];
            int4 t4a = *(const int4*)&cidx[n + 2 * BW];
            int4 t4b = *(const int4*)&cidx[n + 2 * BW + 4];
            ia[0]=t4a.x; ia[1]=t4a.y; ia[2]=t4a.z; ia[3]=t4a.w;
            ia[4]=t4b.x; ia[5]=t4b.y; ia[6]=t4b.z; ia[7]=t4b.w;
        }
        process(pb, ib);
    }

    // ---- Phase 3: write outputs (unchanged) ----
    const size_t pix   = ((size_t)b * H + i) * W + j;
    const size_t plane = (size_t)B * H * W * KPP;
    float vidx[KPP], vzbf[KPP], vdst[KPP];
#pragma unroll
    for (int k = 0; k < KPP; ++k) {
        bool valid = (zb[k] != INFINITY);
        vidx[k] = valid ? (float)id[k] : -1.0f;
        vzbf[k] = valid ? zb[k]        : -1.0f;
        vdst[k] = valid ? dd[k]        : -1.0f;
    }
    float* oidx = out + pix * KPP;
    float* ozbf = out + plane + pix * KPP;
    float* odst = out + 2 * plane + pix * KPP;
    *(float4*)(oidx)     = make_float4(vidx[0], vidx[1], vidx[2], vidx[3]);
    *(float4*)(oidx + 4) = make_float4(vidx[4], vidx[5], vidx[6], vidx[7]);
    *(float4*)(ozbf)     = make_float4(vzbf[0], vzbf[1], vzbf[2], vzbf[3]);
    *(float4*)(ozbf + 4) = make_float4(vzbf[4], vzbf[5], vzbf[6], vzbf[7]);
    *(float4*)(odst)     = make_float4(vdst[0], vdst[1], vdst[2], vdst[3]);
    *(float4*)(odst + 4) = make_float4(vdst[4], vdst[5], vdst[6], vdst[7]);
}

extern "C" void kernel_launch(void* const* d_in, const int* in_sizes, int n_in,
                              void* d_out, int out_size, void* d_ws, size_t ws_size,
                              hipStream_t stream) {
    const float* points = (const float*)d_in[0];
    const float* radius = (const float*)d_in[1];
    const float* w2v    = (const float*)d_in[2];
    const float* proj   = (const float*)d_in[3];
    int B = in_sizes[2] / 16;
    if (B < 1) B = 1;
    int N = in_sizes[1] / B;
    int HW = out_size / (3 * B * KPP);
    int H = 1;
    while ((H + 1) * (H + 1) <= HW) ++H;     // integer sqrt
    int W = H;

    int tiles = (W / 16) * (H / 16);
    dim3 grid(B * tiles);
    dim3 block(256);
    size_t shmem = (size_t)(N + 2 * BW) * (sizeof(float4) + sizeof(int));
    sphere_raster_kernel<<<grid, block, shmem, stream>>>(
        points, radius, w2v, proj, (float*)d_out, B, N, H, W);
}